// Round 1
// baseline (1314.528 us; speedup 1.0000x reference)
//
#include <hip/hip_runtime.h>
#include <math.h>

#define N_NODES   100000
#define N_EDGES   1600000
#define ETOT      1700000   // edges + self loops
#define F_IN      100
#define HEADS     3
#define HEAD_DIM  64
#define HIDDEN    192
#define NUM_GRAPHS 128
#define NUM_CLASSES 2

// ---- ordered-uint encoding for float atomicMax (handles negatives) ----
__device__ __forceinline__ unsigned f2ord(float f) {
    unsigned u = __float_as_uint(f);
    return (u & 0x80000000u) ? ~u : (u | 0x80000000u);
}
__device__ __forceinline__ float ord2f(unsigned u) {
    return __uint_as_float((u & 0x80000000u) ? (u & 0x7fffffffu) : ~u);
}

// ---- K1: h = x@W  (+ per-node a_src/a_dst attention dots) ----
// block = 192 threads (3 waves = 3 heads), 16 nodes per block, grid = 6250
__global__ __launch_bounds__(192) void k_gemm(
        const float* __restrict__ x, const float* __restrict__ W,
        const float* __restrict__ att_src, const float* __restrict__ att_dst,
        float* __restrict__ h, float* __restrict__ asrc, float* __restrict__ adst) {
    const int f = threadIdx.x;          // output feature 0..191
    const int base = blockIdx.x * 16;   // first node of this block

    float acc[16];
#pragma unroll
    for (int i = 0; i < 16; i++) acc[i] = 0.f;

    // x addresses are wave-uniform -> compiler emits scalar loads; W is L2-hot.
    for (int k = 0; k < F_IN; k++) {
        float wv = W[k * HIDDEN + f];
#pragma unroll
        for (int i = 0; i < 16; i++)
            acc[i] += x[(base + i) * F_IN + k] * wv;
    }

    const int head = f >> 6;
    const float ws = att_src[f];   // att_src[head*64 + lane] == att_src[f]
    const float wd = att_dst[f];

#pragma unroll 1
    for (int i = 0; i < 16; i++) {
        const int n = base + i;
        h[n * HIDDEN + f] = acc[i];
        float vs = acc[i] * ws;
        float vd = acc[i] * wd;
#pragma unroll
        for (int off = 32; off; off >>= 1) {
            vs += __shfl_down(vs, off);
            vd += __shfl_down(vd, off);
        }
        if ((f & 63) == 0) {
            asrc[n * HEADS + head] = vs;
            adst[n * HEADS + head] = vd;
        }
    }
}

// ---- K2: histogram of incoming-edge counts per dst ----
__global__ void k_hist(const int* __restrict__ ei, int* __restrict__ count) {
    int i = blockIdx.x * blockDim.x + threadIdx.x;
    if (i >= ETOT) return;
    int d = (i < N_EDGES) ? ei[N_EDGES + i] : (i - N_EDGES);
    atomicAdd(&count[d], 1);
}

// ---- K3: exclusive scan of counts (single block, 1024 threads) ----
__global__ __launch_bounds__(1024) void k_scan(
        const int* __restrict__ count, int* __restrict__ offs, int* __restrict__ cursor) {
    __shared__ int part[1024];
    const int t = threadIdx.x;
    const int CH = 98;                       // 1024*98 >= 100000
    int begin = t * CH;
    int end = begin + CH; if (end > N_NODES) end = N_NODES;
    int s = 0;
    for (int i = begin; i < end && i < N_NODES; i++) s += count[i];
    part[t] = s;
    __syncthreads();
    for (int off = 1; off < 1024; off <<= 1) {
        int v = (t >= off) ? part[t - off] : 0;
        __syncthreads();
        part[t] += v;
        __syncthreads();
    }
    int run = (t == 0) ? 0 : part[t - 1];
    for (int i = begin; i < end && i < N_NODES; i++) {
        offs[i] = run; cursor[i] = run; run += count[i];
    }
    if (t == 1023) offs[N_NODES] = part[1023];
}

// ---- K4: scatter edges into dst-sorted order; precompute leaky-relu'd e ----
__global__ void k_scatter(const int* __restrict__ ei,
        const float* __restrict__ asrc, const float* __restrict__ adst,
        int* __restrict__ cursor, int* __restrict__ srcs, float* __restrict__ evals) {
    int i = blockIdx.x * blockDim.x + threadIdx.x;
    if (i >= ETOT) return;
    int s, d;
    if (i < N_EDGES) { s = ei[i]; d = ei[N_EDGES + i]; }
    else             { s = d = i - N_EDGES; }
    int pos = atomicAdd(&cursor[d], 1);
    srcs[pos] = s;
#pragma unroll
    for (int hh = 0; hh < HEADS; hh++) {
        float e = asrc[s * HEADS + hh] + adst[d * HEADS + hh];
        e = (e > 0.f) ? e : 0.2f * e;       // leaky_relu slope 0.2
        evals[pos * HEADS + hh] = e;
    }
}

// ---- K5: per-node softmax + aggregation + bias + leaky_relu + pool(max) ----
// block = 192 threads (wave == head, lane == channel), one node per block
__global__ __launch_bounds__(192) void k_aggr(const int* __restrict__ offs,
        const int* __restrict__ srcs, const float* __restrict__ evals,
        const float* __restrict__ h, const float* __restrict__ bias,
        const int* __restrict__ batch, unsigned* __restrict__ pooled) {
    const int n = blockIdx.x;
    const int f = threadIdx.x;
    const int head = f >> 6, lane = f & 63;
    const int start = offs[n], end = offs[n + 1];

    // pass 1: max over incoming e (lane-parallel)
    float m = -INFINITY;
    for (int i = start + lane; i < end; i += 64)
        m = fmaxf(m, evals[i * HEADS + head]);
#pragma unroll
    for (int off = 32; off; off >>= 1) m = fmaxf(m, __shfl_down(m, off));
    m = __shfl(m, 0);

    // pass 2: softmax denominator
    float l = 0.f;
    for (int i = start + lane; i < end; i += 64)
        l += expf(evals[i * HEADS + head] - m);
#pragma unroll
    for (int off = 32; off; off >>= 1) l += __shfl_down(l, off);
    l = __shfl(l, 0);
    const float inv = 1.f / l;

    // pass 3: chunked gather-accumulate (coalesced 256B h-row reads per wave)
    float acc = 0.f;
    for (int cb = start; cb < end; cb += 64) {
        int cnt = end - cb; if (cnt > 64) cnt = 64;
        float myalpha = 0.f; int mysrc = 0;
        if (lane < cnt) {
            myalpha = expf(evals[(cb + lane) * HEADS + head] - m) * inv;
            mysrc = srcs[cb + lane];
        }
        for (int j = 0; j < cnt; j++) {
            float a = __shfl(myalpha, j);
            int s = __shfl(mysrc, j);
            acc += a * h[s * HIDDEN + head * HEAD_DIM + lane];
        }
    }

    float v = acc + bias[f];
    v = (v > 0.f) ? v : 0.01f * v;          // F.leaky_relu slope 0.01
    atomicMax(&pooled[batch[n] * HIDDEN + f], f2ord(v));
}

// ---- K6: classifier  logits = pooled @ cls_W + cls_b  (128x2) ----
__global__ __launch_bounds__(256) void k_cls(const unsigned* __restrict__ pooled,
        const float* __restrict__ clsW, const float* __restrict__ clsb,
        float* __restrict__ out) {
    const int t = threadIdx.x;        // 256 threads = 128 graphs x 2 classes
    const int g = t >> 1, c = t & 1;
    float s = clsb[c];
    for (int fi = 0; fi < HIDDEN; fi++)
        s += ord2f(pooled[g * HIDDEN + fi]) * clsW[fi * NUM_CLASSES + c];
    out[g * NUM_CLASSES + c] = s;
}

extern "C" void kernel_launch(void* const* d_in, const int* in_sizes, int n_in,
                              void* d_out, int out_size, void* d_ws, size_t ws_size,
                              hipStream_t stream) {
    const float* x       = (const float*)d_in[0];
    const int*   ei      = (const int*)d_in[1];   // [2, N_EDGES] flat
    const int*   batch   = (const int*)d_in[2];
    const float* W       = (const float*)d_in[3];
    const float* att_src = (const float*)d_in[4];
    const float* att_dst = (const float*)d_in[5];
    const float* bias    = (const float*)d_in[6];
    const float* clsW    = (const float*)d_in[7];
    const float* clsb    = (const float*)d_in[8];
    float* out = (float*)d_out;

    // workspace carve-up (~108 MB total), 256B aligned
    char* p = (char*)d_ws;
    auto alloc = [&](size_t bytes) {
        char* r = p; p += (bytes + 255) & ~size_t(255); return r;
    };
    float*    h      = (float*)   alloc(sizeof(float) * N_NODES * HIDDEN);
    float*    asrc   = (float*)   alloc(sizeof(float) * N_NODES * HEADS);
    float*    adst   = (float*)   alloc(sizeof(float) * N_NODES * HEADS);
    int*      count  = (int*)     alloc(sizeof(int) * N_NODES);
    int*      offs   = (int*)     alloc(sizeof(int) * (N_NODES + 1));
    int*      cursor = (int*)     alloc(sizeof(int) * N_NODES);
    int*      srcs   = (int*)     alloc(sizeof(int) * ETOT);
    float*    evals  = (float*)   alloc(sizeof(float) * ETOT * HEADS);
    unsigned* pooled = (unsigned*)alloc(sizeof(unsigned) * NUM_GRAPHS * HIDDEN);

    hipMemsetAsync(count, 0, sizeof(int) * N_NODES, stream);
    hipMemsetAsync(pooled, 0, sizeof(unsigned) * NUM_GRAPHS * HIDDEN, stream);

    k_gemm<<<N_NODES / 16, 192, 0, stream>>>(x, W, att_src, att_dst, h, asrc, adst);
    k_hist<<<(ETOT + 255) / 256, 256, 0, stream>>>(ei, count);
    k_scan<<<1, 1024, 0, stream>>>(count, offs, cursor);
    k_scatter<<<(ETOT + 255) / 256, 256, 0, stream>>>(ei, asrc, adst, cursor, srcs, evals);
    k_aggr<<<N_NODES, 192, 0, stream>>>(offs, srcs, evals, h, bias, batch, pooled);
    k_cls<<<1, 256, 0, stream>>>(pooled, clsW, clsb, out);
}

// Round 2
// 713.303 us; speedup vs baseline: 1.8429x; 1.8429x over previous
//
#include <hip/hip_runtime.h>
#include <math.h>

#define N_NODES   100000
#define N_EDGES   1600000
#define ETOT      1700000   // edges + self loops
#define F_IN      100
#define HEADS     3
#define HEAD_DIM  64
#define HIDDEN    192
#define NUM_GRAPHS 128
#define NUM_CLASSES 2

// ---- ordered-uint encoding for float atomicMax (handles negatives) ----
__device__ __forceinline__ unsigned f2ord(float f) {
    unsigned u = __float_as_uint(f);
    return (u & 0x80000000u) ? ~u : (u | 0x80000000u);
}
__device__ __forceinline__ float ord2f(unsigned u) {
    return __uint_as_float((u & 0x80000000u) ? (u & 0x7fffffffu) : ~u);
}

// ---- K1: h = x@W. lane=node (64/block-tile), wave=48 features, acc[48].
// x tile in LDS (stride 101 -> 2-way bank alias, free). W row via wave-uniform
// scalar loads (s_load_dwordx4) -> no LDS/VMEM cost in the inner loop.
__global__ __launch_bounds__(256) void k_gemm(
        const float* __restrict__ x, const float* __restrict__ W,
        float* __restrict__ h) {
    __shared__ float xs[64 * 101];
    const int tid = threadIdx.x;
    const int lane = tid & 63;
    const int base = blockIdx.x * 64;

    // stage x tile: 64 nodes x 100 k, coalesced global, strided LDS
    for (int idx = tid; idx < 64 * F_IN; idx += 256) {
        int g = base * F_IN + idx;
        float v = (g < N_NODES * F_IN) ? x[g] : 0.f;
        xs[(idx / F_IN) * 101 + (idx % F_IN)] = v;
    }
    __syncthreads();

    // wave-uniform feature base (forces scalar W loads)
    const int f0 = 48 * __builtin_amdgcn_readfirstlane(tid >> 6);

    float acc[48];
#pragma unroll
    for (int i = 0; i < 48; i++) acc[i] = 0.f;

#pragma unroll 2
    for (int k = 0; k < F_IN; k++) {
        float xk = xs[lane * 101 + k];
        const float4* wrow = (const float4*)(W + k * HIDDEN + f0);
#pragma unroll
        for (int fi = 0; fi < 12; fi++) {
            float4 w = wrow[fi];
            acc[fi * 4 + 0] += xk * w.x;
            acc[fi * 4 + 1] += xk * w.y;
            acc[fi * 4 + 2] += xk * w.z;
            acc[fi * 4 + 3] += xk * w.w;
        }
    }

    const int node = base + lane;
    if (node < N_NODES) {
        float4* hp = (float4*)(h + node * HIDDEN + f0);
#pragma unroll
        for (int fi = 0; fi < 12; fi++)
            hp[fi] = make_float4(acc[fi * 4 + 0], acc[fi * 4 + 1],
                                 acc[fi * 4 + 2], acc[fi * 4 + 3]);
    }
}

// ---- K1b: wsv[k][j] = sum_c W[k][ (j%3)*64+c ] * att_{src|dst}[j%3][c] ----
__global__ __launch_bounds__(640) void k_attprep(
        const float* __restrict__ W, const float* __restrict__ att_src,
        const float* __restrict__ att_dst, float* __restrict__ wsv) {
    int t = threadIdx.x;
    if (t >= 600) return;
    int k = t / 6, j = t % 6;
    const float* a = (j < 3) ? att_src : att_dst;
    int hh = j % 3;
    float s = 0.f;
    for (int c = 0; c < HEAD_DIM; c++)
        s += W[k * HIDDEN + hh * HEAD_DIM + c] * a[hh * HEAD_DIM + c];
    wsv[k * 6 + j] = s;
}

// ---- K1c: asrc/adst = x @ wsv  (wave per node, coalesced x reads) ----
__global__ __launch_bounds__(256) void k_att(
        const float* __restrict__ x, const float* __restrict__ wsv,
        float* __restrict__ asrc, float* __restrict__ adst) {
    const int lane = threadIdx.x & 63;
    const int nid = blockIdx.x * 4 + (threadIdx.x >> 6);
    float xv0 = x[nid * F_IN + lane];
    int l2 = (lane < F_IN - 64) ? (64 + lane) : 0;
    float xv1 = (lane < F_IN - 64) ? x[nid * F_IN + 64 + lane] : 0.f;
    float p[6];
#pragma unroll
    for (int j = 0; j < 6; j++)
        p[j] = xv0 * wsv[lane * 6 + j] + xv1 * wsv[l2 * 6 + j];
#pragma unroll
    for (int j = 0; j < 6; j++)
#pragma unroll
        for (int msk = 1; msk < 64; msk <<= 1)
            p[j] += __shfl_xor(p[j], msk);
    if (lane < 3) {
        asrc[nid * HEADS + lane] = p[lane];
        adst[nid * HEADS + lane] = p[3 + lane];
    }
}

// ---- K2: histogram of incoming-edge counts per dst ----
__global__ void k_hist(const int* __restrict__ ei, int* __restrict__ count) {
    int i = blockIdx.x * blockDim.x + threadIdx.x;
    if (i >= ETOT) return;
    int d = (i < N_EDGES) ? ei[N_EDGES + i] : (i - N_EDGES);
    atomicAdd(&count[d], 1);
}

// ---- K3: exclusive scan, wave-parallel two-phase (single block) ----
__global__ __launch_bounds__(1024) void k_scan(
        const int* __restrict__ count, int* __restrict__ offs, int* __restrict__ cursor) {
    __shared__ int wsum[16];
    __shared__ int wexc[16];
    const int t = threadIdx.x, w = t >> 6, lane = t & 63;
    const int CH = N_NODES / 16;            // 6250, exact
    const int begin = w * CH, end = begin + CH;

    int s = 0;
    for (int i = begin + lane; i < end; i += 64) s += count[i];
#pragma unroll
    for (int off = 32; off; off >>= 1) s += __shfl_down(s, off);
    if (lane == 0) wsum[w] = s;
    __syncthreads();
    if (t == 0) {
        int run = 0;
        for (int i = 0; i < 16; i++) { wexc[i] = run; run += wsum[i]; }
        offs[N_NODES] = run;
    }
    __syncthreads();

    int running = wexc[w];
    for (int cb = begin; cb < end; cb += 64) {
        int i = cb + lane;
        int v = (i < end) ? count[i] : 0;
        int sc = v;
#pragma unroll
        for (int off = 1; off < 64; off <<= 1) {
            int u = __shfl_up(sc, off);
            if (lane >= off) sc += u;
        }
        if (i < end) { int e = running + sc - v; offs[i] = e; cursor[i] = e; }
        running += __shfl(sc, 63);
    }
}

// ---- K4: scatter edges into dst-sorted order; precompute leaky-relu'd e ----
__global__ void k_scatter(const int* __restrict__ ei,
        const float* __restrict__ asrc, const float* __restrict__ adst,
        int* __restrict__ cursor, int* __restrict__ srcs, float* __restrict__ evals) {
    int i = blockIdx.x * blockDim.x + threadIdx.x;
    if (i >= ETOT) return;
    int s, d;
    if (i < N_EDGES) { s = ei[i]; d = ei[N_EDGES + i]; }
    else             { s = d = i - N_EDGES; }
    int pos = atomicAdd(&cursor[d], 1);
    srcs[pos] = s;
#pragma unroll
    for (int hh = 0; hh < HEADS; hh++) {
        float e = asrc[s * HEADS + hh] + adst[d * HEADS + hh];
        e = (e > 0.f) ? e : 0.2f * e;       // leaky_relu slope 0.2
        evals[pos * HEADS + hh] = e;
    }
}

// ---- K5: per-node softmax + aggregation + bias + leaky_relu + pool(max) ----
__global__ __launch_bounds__(192) void k_aggr(const int* __restrict__ offs,
        const int* __restrict__ srcs, const float* __restrict__ evals,
        const float* __restrict__ h, const float* __restrict__ bias,
        const int* __restrict__ batch, unsigned* __restrict__ pooled) {
    const int n = blockIdx.x;
    const int f = threadIdx.x;
    const int head = f >> 6, lane = f & 63;
    const int start = offs[n], end = offs[n + 1];

    float m = -INFINITY;
    for (int i = start + lane; i < end; i += 64)
        m = fmaxf(m, evals[i * HEADS + head]);
#pragma unroll
    for (int off = 32; off; off >>= 1) m = fmaxf(m, __shfl_down(m, off));
    m = __shfl(m, 0);

    float l = 0.f;
    for (int i = start + lane; i < end; i += 64)
        l += expf(evals[i * HEADS + head] - m);
#pragma unroll
    for (int off = 32; off; off >>= 1) l += __shfl_down(l, off);
    l = __shfl(l, 0);
    const float inv = 1.f / l;

    const float* hp = h + head * HEAD_DIM + lane;
    float acc = 0.f;
    for (int cb = start; cb < end; cb += 64) {
        int cnt = end - cb; if (cnt > 64) cnt = 64;
        float myalpha = 0.f; int mysrc = 0;
        if (lane < cnt) {
            myalpha = expf(evals[(cb + lane) * HEADS + head] - m) * inv;
            mysrc = srcs[cb + lane];
        }
        int j = 0;
        for (; j + 4 <= cnt; j += 4) {
            float a0 = __shfl(myalpha, j + 0); int s0 = __shfl(mysrc, j + 0);
            float a1 = __shfl(myalpha, j + 1); int s1 = __shfl(mysrc, j + 1);
            float a2 = __shfl(myalpha, j + 2); int s2 = __shfl(mysrc, j + 2);
            float a3 = __shfl(myalpha, j + 3); int s3 = __shfl(mysrc, j + 3);
            float h0 = hp[s0 * HIDDEN];
            float h1 = hp[s1 * HIDDEN];
            float h2 = hp[s2 * HIDDEN];
            float h3 = hp[s3 * HIDDEN];
            acc += a0 * h0; acc += a1 * h1; acc += a2 * h2; acc += a3 * h3;
        }
        for (; j < cnt; j++) {
            float a = __shfl(myalpha, j); int s = __shfl(mysrc, j);
            acc += a * hp[s * HIDDEN];
        }
    }

    float v = acc + bias[f];
    v = (v > 0.f) ? v : 0.01f * v;          // F.leaky_relu slope 0.01
    atomicMax(&pooled[batch[n] * HIDDEN + f], f2ord(v));
}

// ---- K6: classifier  logits = pooled @ cls_W + cls_b  (128x2) ----
__global__ __launch_bounds__(256) void k_cls(const unsigned* __restrict__ pooled,
        const float* __restrict__ clsW, const float* __restrict__ clsb,
        float* __restrict__ out) {
    const int t = threadIdx.x;
    const int g = t >> 1, c = t & 1;
    float s = clsb[c];
    for (int fi = 0; fi < HIDDEN; fi++)
        s += ord2f(pooled[g * HIDDEN + fi]) * clsW[fi * NUM_CLASSES + c];
    out[g * NUM_CLASSES + c] = s;
}

extern "C" void kernel_launch(void* const* d_in, const int* in_sizes, int n_in,
                              void* d_out, int out_size, void* d_ws, size_t ws_size,
                              hipStream_t stream) {
    const float* x       = (const float*)d_in[0];
    const int*   ei      = (const int*)d_in[1];   // [2, N_EDGES] flat
    const int*   batch   = (const int*)d_in[2];
    const float* W       = (const float*)d_in[3];
    const float* att_src = (const float*)d_in[4];
    const float* att_dst = (const float*)d_in[5];
    const float* bias    = (const float*)d_in[6];
    const float* clsW    = (const float*)d_in[7];
    const float* clsb    = (const float*)d_in[8];
    float* out = (float*)d_out;

    char* p = (char*)d_ws;
    auto alloc = [&](size_t bytes) {
        char* r = p; p += (bytes + 255) & ~size_t(255); return r;
    };
    float*    h      = (float*)   alloc(sizeof(float) * N_NODES * HIDDEN);
    float*    asrc   = (float*)   alloc(sizeof(float) * N_NODES * HEADS);
    float*    adst   = (float*)   alloc(sizeof(float) * N_NODES * HEADS);
    int*      count  = (int*)     alloc(sizeof(int) * N_NODES);
    int*      offs   = (int*)     alloc(sizeof(int) * (N_NODES + 1));
    int*      cursor = (int*)     alloc(sizeof(int) * N_NODES);
    int*      srcs   = (int*)     alloc(sizeof(int) * ETOT);
    float*    evals  = (float*)   alloc(sizeof(float) * ETOT * HEADS);
    float*    wsv    = (float*)   alloc(sizeof(float) * F_IN * 6);
    unsigned* pooled = (unsigned*)alloc(sizeof(unsigned) * NUM_GRAPHS * HIDDEN);

    hipMemsetAsync(count, 0, sizeof(int) * N_NODES, stream);
    hipMemsetAsync(pooled, 0, sizeof(unsigned) * NUM_GRAPHS * HIDDEN, stream);

    k_attprep<<<1, 640, 0, stream>>>(W, att_src, att_dst, wsv);
    k_att<<<N_NODES / 4, 256, 0, stream>>>(x, wsv, asrc, adst);
    k_hist<<<(ETOT + 255) / 256, 256, 0, stream>>>(ei, count);
    k_scan<<<1, 1024, 0, stream>>>(count, offs, cursor);
    k_scatter<<<(ETOT + 255) / 256, 256, 0, stream>>>(ei, asrc, adst, cursor, srcs, evals);
    k_gemm<<<(N_NODES + 63) / 64, 256, 0, stream>>>(x, W, h);
    k_aggr<<<N_NODES, 192, 0, stream>>>(offs, srcs, evals, h, bias, batch, pooled);
    k_cls<<<1, 256, 0, stream>>>(pooled, clsW, clsb, out);
}